// Round 2
// baseline (1015.225 us; speedup 1.0000x reference)
//
#include <hip/hip_runtime.h>
#include <stdint.h>

#define HID 2048

// ---------------- threefry2x32 (JAX-compatible) ----------------
__device__ __forceinline__ uint32_t rotl32(uint32_t v, int r){ return (v<<r)|(v>>(32-r)); }

__device__ __forceinline__ void tf2x32(uint32_t k0, uint32_t k1, uint32_t x0, uint32_t x1,
                                       uint32_t& o0, uint32_t& o1){
  uint32_t ks2 = k0 ^ k1 ^ 0x1BD11BDAu;
  x0 += k0; x1 += k1;
  // rounds 1-4 (13,15,26,6)
  x0+=x1; x1=rotl32(x1,13); x1^=x0;
  x0+=x1; x1=rotl32(x1,15); x1^=x0;
  x0+=x1; x1=rotl32(x1,26); x1^=x0;
  x0+=x1; x1=rotl32(x1,6);  x1^=x0;
  x0+=k1; x1+=ks2+1u;
  // rounds 5-8 (17,29,16,24)
  x0+=x1; x1=rotl32(x1,17); x1^=x0;
  x0+=x1; x1=rotl32(x1,29); x1^=x0;
  x0+=x1; x1=rotl32(x1,16); x1^=x0;
  x0+=x1; x1=rotl32(x1,24); x1^=x0;
  x0+=ks2; x1+=k0+2u;
  // rounds 9-12 (13,15,26,6)
  x0+=x1; x1=rotl32(x1,13); x1^=x0;
  x0+=x1; x1=rotl32(x1,15); x1^=x0;
  x0+=x1; x1=rotl32(x1,26); x1^=x0;
  x0+=x1; x1=rotl32(x1,6);  x1^=x0;
  x0+=k0; x1+=k1+3u;
  // rounds 13-16 (17,29,16,24)
  x0+=x1; x1=rotl32(x1,17); x1^=x0;
  x0+=x1; x1=rotl32(x1,29); x1^=x0;
  x0+=x1; x1=rotl32(x1,16); x1^=x0;
  x0+=x1; x1=rotl32(x1,24); x1^=x0;
  x0+=k1; x1+=ks2+4u;
  // rounds 17-20 (13,15,26,6)
  x0+=x1; x1=rotl32(x1,13); x1^=x0;
  x0+=x1; x1=rotl32(x1,15); x1^=x0;
  x0+=x1; x1=rotl32(x1,26); x1^=x0;
  x0+=x1; x1=rotl32(x1,6);  x1^=x0;
  x0+=ks2; x1+=k0+5u;
  o0=x0; o1=x1;
}

// jax.random.categorical with jax_threefry_partitionable=True (modern JAX default):
//   skey, sk = split(skey): row i = full threefry(key, (hi=0, lo=i)) word pair
//   random_bits(sk, 32, (k,)): element i = y0 ^ y1 of threefry(sk, (0, i))
//   uniform -> gumbel -> first-occurrence argmax(logits + gumbel)
// Also accumulates log_p and entropy like the reference (log_softmax math).
__device__ void do_sample(const float* logits, int k, uint32_t* key, float* sc,
                          int* action_out, int* xidx, int xoff){
  float m = logits[0];
  for (int i=1;i<k;i++) m = fmaxf(m, logits[i]);
  float se = 0.f;
  for (int i=0;i<k;i++) se += expf(logits[i]-m);
  float lse = logf(se);

  // partitionable split(skey) -> new carry key (counter 0), sample key (counter 1)
  uint32_t n0,n1,s0,s1;
  tf2x32(key[0],key[1],0u,0u,n0,n1);
  tf2x32(key[0],key[1],0u,1u,s0,s1);
  key[0]=n0; key[1]=n1;

  float best=-3.0e38f; int act=0;
  for (int i=0;i<k;i++){
    uint32_t y0,y1; tf2x32(s0,s1,0u,(uint32_t)i,y0,y1);
    uint32_t bits = y0 ^ y1;                                      // 32-bit fold
    float f = __uint_as_float((bits>>9)|0x3f800000u) - 1.0f;      // [0,1)
    float u = fmaxf(f, 1.17549435e-38f);                          // minval=tiny
    float g = -logf(-logf(u));                                    // gumbel
    float z = logits[i]+g;
    if (z>best){best=z; act=i;}                                   // first-max argmax
  }
  float ent=0.f;
  for (int i=0;i<k;i++){ float lp=logits[i]-m-lse; ent -= lp*expf(lp); }
  sc[0] += logits[act]-m-lse;
  sc[1] += ent;
  *action_out = act;
  *xidx = act + xoff;
}

// ---------------- init ----------------
__global__ void init_kernel(float* h0, float* c, float* sc, uint32_t* key, int* xidx){
  int tid = blockIdx.x*blockDim.x + threadIdx.x;
  if (tid < HID){ h0[tid]=0.f; c[tid]=0.f; }
  if (tid==0){ sc[0]=0.f; sc[1]=0.f; key[0]=0u; key[1]=42u; xidx[0]=19; }
}

// ---------------- E = emb[0:8] @ W_emb_attn.T  (8 x 2048) ----------------
__global__ __launch_bounds__(256) void eproj_kernel(const float* __restrict__ emb,
                                                    const float* __restrict__ Wq,
                                                    float* __restrict__ E){
  int w = (blockIdx.x*256 + threadIdx.x) >> 6;  // output column j of E
  int lane = threadIdx.x & 63;
  if (w >= HID) return;
  const float4* W4 = (const float4*)(Wq + (size_t)w*HID);
  float acc[8];
  #pragma unroll
  for (int i=0;i<8;i++) acc[i]=0.f;
  #pragma unroll
  for (int it=0; it<8; ++it){
    float4 wv = W4[it*64 + lane];
    #pragma unroll
    for (int i=0;i<8;i++){
      float4 ev = ((const float4*)(emb + (size_t)i*HID))[it*64+lane];
      acc[i] += wv.x*ev.x + wv.y*ev.y + wv.z*ev.z + wv.w*ev.w;
    }
  }
  #pragma unroll
  for (int i=0;i<8;i++){
    float v = acc[i];
    #pragma unroll
    for (int s=32;s;s>>=1) v += __shfl_xor(v, s);
    if (lane==0) E[(size_t)i*HID + w] = v;
  }
}

// ---------------- P[e] = W_ih @ emb[e] + b_ih + b_hh  (20 x 8192; row 19 = bias only) ----------------
__global__ __launch_bounds__(256) void pproj_kernel(const float* __restrict__ Wih,
                                                    const float* __restrict__ emb,
                                                    const float* __restrict__ bih,
                                                    const float* __restrict__ bhh,
                                                    float* __restrict__ P){
  int j = (blockIdx.x*256 + threadIdx.x) >> 6;   // gate row 0..8191
  int lane = threadIdx.x & 63;
  if (j >= 4*HID) return;
  const float4* W4 = (const float4*)(Wih + (size_t)j*HID);
  float acc[19];
  #pragma unroll
  for (int e=0;e<19;e++) acc[e]=0.f;
  #pragma unroll
  for (int it=0; it<8; ++it){
    float4 wv = W4[it*64 + lane];
    #pragma unroll
    for (int e=0;e<19;e++){
      float4 ev = ((const float4*)(emb + (size_t)e*HID))[it*64+lane];
      acc[e] += wv.x*ev.x + wv.y*ev.y + wv.z*ev.z + wv.w*ev.w;
    }
  }
  #pragma unroll
  for (int e=0;e<19;e++){
    float v = acc[e];
    #pragma unroll
    for (int s=32;s;s>>=1) v += __shfl_xor(v, s);
    acc[e]=v;
  }
  if (lane==0){
    float b = bih[j] + bhh[j];
    #pragma unroll
    for (int e=0;e<19;e++) P[(size_t)e*4*HID + j] = acc[e] + b;
    P[(size_t)19*4*HID + j] = b;
  }
}

// ---------------- fused LSTM step: gates = P[xidx] + W_hh @ h; pointwise ----------------
__global__ __launch_bounds__(256) void lstm_kernel(const float* __restrict__ Whh,
                                                   const float* __restrict__ P,
                                                   const int* __restrict__ xidx,
                                                   const float* __restrict__ hin,
                                                   float* __restrict__ hout,
                                                   float* __restrict__ c){
  int t = (blockIdx.x*256 + threadIdx.x) >> 6;   // hidden element 0..2047
  int lane = threadIdx.x & 63;
  if (t >= HID) return;
  int xi = xidx[0];
  const float4* h4 = (const float4*)hin;
  float acc[4] = {0.f,0.f,0.f,0.f};
  #pragma unroll
  for (int it=0; it<8; ++it){
    float4 hv = h4[it*64 + lane];
    #pragma unroll
    for (int g=0; g<4; ++g){
      const float4* wh = (const float4*)(Whh + ((size_t)g*HID + t)*HID);
      float4 w = wh[it*64 + lane];
      acc[g] += w.x*hv.x + w.y*hv.y + w.z*hv.z + w.w*hv.w;
    }
  }
  #pragma unroll
  for (int g=0; g<4; ++g){
    float v = acc[g];
    #pragma unroll
    for (int s=32;s;s>>=1) v += __shfl_xor(v, s);
    acc[g]=v;
  }
  if (lane==0){
    const float* Pr = P + (size_t)xi*4*HID;
    float gi = acc[0] + Pr[t];
    float gf = acc[1] + Pr[HID+t];
    float gg = acc[2] + Pr[2*HID+t];
    float go = acc[3] + Pr[3*HID+t];
    float si = 1.f/(1.f+expf(-gi));
    float sf = 1.f/(1.f+expf(-gf));
    float so = 1.f/(1.f+expf(-go));
    float c2 = sf*c[t] + si*tanhf(gg);
    float h2 = so*tanhf(c2);
    c[t]=c2; hout[t]=h2;
  }
}

// ---------------- a = W_hid_attn @ h ----------------
__global__ __launch_bounds__(256) void hproj_kernel(const float* __restrict__ Wh,
                                                    const float* __restrict__ h,
                                                    float* __restrict__ a){
  int j = (blockIdx.x*256 + threadIdx.x) >> 6;
  int lane = threadIdx.x & 63;
  if (j >= HID) return;
  const float4* W4 = (const float4*)(Wh + (size_t)j*HID);
  const float4* h4 = (const float4*)h;
  float acc=0.f;
  #pragma unroll
  for (int it=0; it<8; ++it){
    float4 w = W4[it*64+lane];
    float4 hv = h4[it*64+lane];
    acc += w.x*hv.x + w.y*hv.y + w.z*hv.z + w.w*hv.w;
  }
  #pragma unroll
  for (int s=32;s;s>>=1) acc += __shfl_xor(acc, s);
  if (lane==0) a[j]=acc;
}

// ---------------- attention logits + sample (single block) ----------------
__global__ __launch_bounds__(256) void attn_sample_kernel(const float* __restrict__ E,
                                                          const float* __restrict__ a,
                                                          const float* __restrict__ Wv,
                                                          float* sc, uint32_t* key, int* xidx,
                                                          int* action_slot, int k){
  __shared__ float sred[8][4];
  int tid = threadIdx.x, lane = tid & 63, wid = tid >> 6;
  float part[8];
  #pragma unroll
  for (int i=0;i<8;i++) part[i]=0.f;
  for (int j = tid; j < HID; j += 256){
    float av = a[j], wv = Wv[j];
    #pragma unroll
    for (int i=0;i<8;i++){
      if (i < k) part[i] += tanhf(E[(size_t)i*HID + j] + av) * wv;
    }
  }
  #pragma unroll
  for (int i=0;i<8;i++){
    float v = part[i];
    #pragma unroll
    for (int s=32;s;s>>=1) v += __shfl_xor(v, s);
    if (lane==0) sred[i][wid]=v;
  }
  __syncthreads();
  if (tid==0){
    float logits[8];
    for (int i=0;i<k;i++){
      float s = sred[i][0]+sred[i][1]+sred[i][2]+sred[i][3];
      logits[i] = 2.5f * tanhf(s * (1.0f/5.0f));
    }
    do_sample(logits, k, key, sc, action_slot, xidx, 0);
  }
}

// ---------------- op logits + sample (single block) ----------------
__global__ __launch_bounds__(256) void op_sample_kernel(const float* __restrict__ Wsoft,
                                                        const float* __restrict__ bsoft,
                                                        const float* __restrict__ h,
                                                        float* sc, uint32_t* key, int* xidx,
                                                        int* action_slot){
  __shared__ float sred[11][4];
  int tid = threadIdx.x, lane = tid & 63, wid = tid >> 6;
  float part[11];
  #pragma unroll
  for (int i=0;i<11;i++) part[i]=0.f;
  for (int j = tid; j < HID; j += 256){
    float hv = h[j];
    #pragma unroll
    for (int i=0;i<11;i++) part[i] += Wsoft[(size_t)i*HID + j] * hv;
  }
  #pragma unroll
  for (int i=0;i<11;i++){
    float v = part[i];
    #pragma unroll
    for (int s=32;s;s>>=1) v += __shfl_xor(v, s);
    if (lane==0) sred[i][wid]=v;
  }
  __syncthreads();
  if (tid==0){
    float logits[11];
    for (int i=0;i<11;i++){
      float s = sred[i][0]+sred[i][1]+sred[i][2]+sred[i][3] + bsoft[i];
      logits[i] = tanhf(s * (1.0f/5.0f));   // (2.5/2.5) * tanh(x/5)
    }
    do_sample(logits, 11, key, sc, action_slot, xidx, 8);  // inp_idx = action + N_NODES + 1
  }
}

// ---------------- write outputs ----------------
__global__ void finalize_kernel(const int* __restrict__ actions, const float* __restrict__ sc,
                                float* __restrict__ out){
  int tid = threadIdx.x;
  if (tid < 28) out[tid] = (float)actions[tid];
  if (tid == 28) out[28] = sc[0];
  if (tid == 29) out[29] = sc[1];
}

extern "C" void kernel_launch(void* const* d_in, const int* in_sizes, int n_in,
                              void* d_out, int out_size, void* d_ws, size_t ws_size,
                              hipStream_t stream) {
  const float* emb   = (const float*)d_in[0];
  const float* Wq    = (const float*)d_in[1];  // W_emb_attn
  const float* Wh    = (const float*)d_in[2];  // W_hid_attn
  const float* Wv    = (const float*)d_in[3];  // W_v_attn
  const float* Wsoft = (const float*)d_in[4];
  const float* bsoft = (const float*)d_in[5];
  const float* Wih   = (const float*)d_in[6];
  const float* Whh   = (const float*)d_in[7];
  const float* bih   = (const float*)d_in[8];
  const float* bhh   = (const float*)d_in[9];
  float* out = (float*)d_out;

  float* ws = (float*)d_ws;
  float* h0 = ws;                 // 2048
  float* h1 = ws + 2048;          // 2048
  float* c  = ws + 4096;          // 2048
  float* a  = ws + 6144;          // 2048
  float* E  = ws + 8192;          // 8*2048
  float* P  = ws + 8192 + 8*2048; // 20*8192
  float* sc = P + 20*4*HID;       // 2 floats
  uint32_t* key = (uint32_t*)(sc + 2);
  int* xidx     = (int*)(sc + 4);
  int* actions  = (int*)(sc + 5); // 28 ints

  init_kernel<<<8,256,0,stream>>>(h0, c, sc, key, xidx);
  eproj_kernel<<<512,256,0,stream>>>(emb, Wq, E);
  pproj_kernel<<<2048,256,0,stream>>>(Wih, emb, bih, bhh, P);

  float* hbuf[2] = {h0, h1};
  int cur = 0, ns = 0, os = 0;
  for (int node = 0; node < 7; ++node){
    for (int i = 0; i < 2; ++i){
      lstm_kernel<<<512,256,0,stream>>>(Whh, P, xidx, hbuf[cur], hbuf[cur^1], c);
      cur ^= 1;
      hproj_kernel<<<512,256,0,stream>>>(Wh, hbuf[cur], a);
      attn_sample_kernel<<<1,256,0,stream>>>(E, a, Wv, sc, key, xidx, actions + ns, node + 2);
      ns++;
    }
    for (int i = 0; i < 2; ++i){
      lstm_kernel<<<512,256,0,stream>>>(Whh, P, xidx, hbuf[cur], hbuf[cur^1], c);
      cur ^= 1;
      op_sample_kernel<<<1,256,0,stream>>>(Wsoft, bsoft, hbuf[cur], sc, key, xidx, actions + 14 + os);
      os++;
    }
  }
  finalize_kernel<<<1,64,0,stream>>>(actions, sc, out);
}